// Round 11
// baseline (371.676 us; speedup 1.0000x reference)
//
#include <hip/hip_runtime.h>
#include <math.h>

#define Hh 256
#define Dd 64
#define Nn 32
#define MS 264   // stride (shorts): 528 B/row
#define AS 33    // Aug stride (floats)

typedef __attribute__((ext_vector_type(8))) short bf8_t;
typedef __attribute__((ext_vector_type(4))) float f4_t;

// round-nearest (pack kernel only; weights deserve RN)
__device__ __forceinline__ short f2bf_rn(float f) {
  union { float f; unsigned u; } v; v.f = f;
  unsigned r = v.u + 0x7FFFu + ((v.u >> 16) & 1u);
  return (short)(r >> 16);
}
// truncating (hot path: 1 inst)
__device__ __forceinline__ short f2bf(float f) {
  union { float f; unsigned u; } v; v.f = f;
  return (short)(v.u >> 16);
}
__device__ __forceinline__ float bf2f(short s) {
  union { unsigned u; float f; } v;
  v.u = ((unsigned)(unsigned short)s) << 16;
  return v.f;
}
// {bf16(hi),bf16(lo)} packed into one dword via v_perm (truncating)
__device__ __forceinline__ unsigned pk2(float hi, float lo) {
  union { float f; unsigned u; } a, b; a.f = hi; b.f = lo;
  return __builtin_amdgcn_perm(a.u, b.u, 0x07060302u);
}
__device__ __forceinline__ bf8_t pack8(f4_t lo, f4_t hi) {
  union { unsigned u[4]; bf8_t v; } r;
  r.u[0] = pk2(lo.y, lo.x);
  r.u[1] = pk2(lo.w, lo.z);
  r.u[2] = pk2(hi.y, hi.x);
  r.u[3] = pk2(hi.w, hi.z);
  return r.v;
}
__device__ __forceinline__ void bf8_to_f(bf8_t v, f4_t& lo, f4_t& hi) {
  union { bf8_t v; unsigned u[4]; } s; s.v = v;
  union { unsigned u; float f; } t;
  t.u = __builtin_amdgcn_perm(s.u[0], 0u, 0x05040100u); lo.x = t.f;
  t.u = __builtin_amdgcn_perm(s.u[0], 0u, 0x07060100u); lo.y = t.f;
  t.u = __builtin_amdgcn_perm(s.u[1], 0u, 0x05040100u); lo.z = t.f;
  t.u = __builtin_amdgcn_perm(s.u[1], 0u, 0x07060100u); lo.w = t.f;
  t.u = __builtin_amdgcn_perm(s.u[2], 0u, 0x05040100u); hi.x = t.f;
  t.u = __builtin_amdgcn_perm(s.u[2], 0u, 0x07060100u); hi.y = t.f;
  t.u = __builtin_amdgcn_perm(s.u[3], 0u, 0x05040100u); hi.z = t.f;
  t.u = __builtin_amdgcn_perm(s.u[3], 0u, 0x07060100u); hi.w = t.f;
}
__device__ __forceinline__ void act012(int net, float z, float& f0, float& f1, float& f2) {
  if (net == 0) {
    float e = __expf(-z);
    float sg = 1.f / (1.f + e);
    f0 = (z > 20.f) ? z : __logf(1.f + __expf(z));
    f1 = sg; f2 = sg * (1.f - sg);
  } else {
    float az = fabsf(z);
    float e = __expf(-az);
    float th = (1.f - e) / (1.f + e);
    th = (z < 0.f) ? -th : th;
    float sech2 = 1.f - th * th;
    f0 = z * th;
    f1 = th + 0.5f * z * sech2;
    f2 = sech2 * (1.f - 0.5f * z * th);
  }
}
__device__ __forceinline__ void act12(int net, float z, float& g1, float& g2) {
  if (net == 0) {
    float e = __expf(-z);
    float sg = 1.f / (1.f + e);
    g1 = sg; g2 = sg * (1.f - sg);
  } else {
    float az = fabsf(z);
    float e = __expf(-az);
    float th = (1.f - e) / (1.f + e);
    th = (z < 0.f) ? -th : th;
    float sech2 = 1.f - th * th;
    g1 = th + 0.5f * z * sech2;
    g2 = sech2 * (1.f - 0.5f * z * th);
  }
}

// ---- pre-pack (RN rounding) ----
// ws4[net*65536 + c*256 + k]             = bf16(W2[k][c])
// ws5[net*65536 + k*256 + j]             = bf16(W2[k][j])
// ws1[((net*2+mt)*8+kb)*512 + lane*8+jj] = bf16(W1[32+mt*16+(lane&15)][kb*32+(lane>>4)*8+jj])
// ws6[net*16384 + t*64 + i]              = bf16(W1[i][t])
__global__ void pack_kernel(const float* __restrict__ mW1, const float* __restrict__ mW2,
                            const float* __restrict__ qW1, const float* __restrict__ qW2,
                            short* __restrict__ ws4, short* __restrict__ ws5,
                            short* __restrict__ ws1, short* __restrict__ ws6) {
  int id = blockIdx.x * 256 + threadIdx.x;
  if (id < 131072) {
    int net = id >> 16;
    const float* W2 = net ? qW2 : mW2;
    int c = (id >> 8) & 255, k = id & 255;
    ws4[id] = f2bf_rn(W2[k * Hh + c]);
  } else if (id < 262144) {
    int id2 = id - 131072;
    int net = id2 >> 16;
    const float* W2 = net ? qW2 : mW2;
    int k = (id2 >> 8) & 255, j = id2 & 255;
    ws5[id2] = f2bf_rn(W2[k * Hh + j]);
  } else if (id < 278528) {
    int id2 = id - 262144;
    int net = id2 >> 13, r = id2 & 8191;
    const float* W1 = net ? qW1 : mW1;
    int mt = r >> 12, kb = (r >> 9) & 7, lane = (r >> 3) & 63, jj = r & 7;
    int m = Nn + mt * 16 + (lane & 15);
    int k = kb * 32 + (lane >> 4) * 8 + jj;
    ws1[id2] = f2bf_rn(W1[m * Hh + k]);
  } else if (id < 311296) {
    int id3 = id - 278528;
    int net = id3 >> 14, r = id3 & 16383;
    const float* W1 = net ? qW1 : mW1;
    int tc = r >> 6, i = r & 63;
    ws6[id3] = f2bf_rn(W1[i * Hh + tc]);
  }
}

__global__ __launch_bounds__(256, 2) void lnn_kernel(
    const float* __restrict__ x,
    const float* __restrict__ mW1, const float* __restrict__ mb1,
    const float* __restrict__ mW2, const float* __restrict__ mb2,
    const float* __restrict__ mW3,
    const float* __restrict__ qW1, const float* __restrict__ qb1,
    const float* __restrict__ qW2, const float* __restrict__ qb2,
    const float* __restrict__ qW3,
    const short* __restrict__ ws4, const short* __restrict__ ws5,
    const short* __restrict__ ws1, const short* __restrict__ ws6,
    float* __restrict__ out)
{
  const int t = threadIdx.x;
  const int w = t >> 6, lane = t & 63, q = lane >> 4, ln16 = lane & 15;
  const int s0 = blockIdx.x * 2;

  __shared__ __align__(16) short megaA[64 * MS];      // staged A-tiles; T written back in place
  __shared__ __align__(16) short Vb[16 * MS];         // vec tile; Aug alias at end
  __shared__ __align__(16) float xr[2][Dd];
  __shared__ __align__(16) short act1s[2 * Hh], d2as[2 * Hh], rb2[2 * Hh], bco2[2 * Hh], tb2[2 * Hh];
  __shared__ __align__(16) float buf1[2][Hh];         // z2pre -> v
  __shared__ float jacv[2 * Nn], Bq1v[2 * Nn], Bq2v[2 * Nn];
  float* AugF = (float*)Vb;

  if (t < 128) ((float*)xr)[t] = x[s0 * Dd + t];
  __syncthreads();

  f4_t sacc0 = {0.f,0.f,0.f,0.f}, sacc1 = {0.f,0.f,0.f,0.f};
  f4_t bq1acc = {0.f,0.f,0.f,0.f}, bq2acc = {0.f,0.f,0.f,0.f};
  float jA = 0.f, jB = 0.f;
  const int mtS = w >> 1, ntS = w & 1;
  const int esT = w >> 1;
  const int esW = w & 1;
  const int rg = w * 8 + (lane >> 3);
  const int kc = (lane & 7) * 32;
  const bf8_t z8 = {0,0,0,0,0,0,0,0};

  for (int net = 0; net < 2; ++net) {
    const float* W1 = net ? qW1 : mW1;
    const float* b1 = net ? qb1 : mb1;
    const float* b2 = net ? qb2 : mb2;
    const float* W3 = net ? qW3 : mW3;
    const short* w4 = ws4 + net * 65536;
    const short* w5 = ws5 + net * 65536;
    const short* w1f = ws1 + net * 8192;
    const short* w6 = ws6 + net * 16384 + t * 64;

    // ===== P1a: z1 + rbuf (both samples), act derivatives, vec rows =====
    {
      float b1t = b1[t];
      float zA = b1t, zB = b1t, rA = 0.f, rB = 0.f;
      #pragma unroll
      for (int ib = 0; ib < 8; ++ib) {
        bf8_t w8 = *(const bf8_t*)&w6[ib * 8];
        f4_t lo, hi; bf8_to_f(w8, lo, hi);
        f4_t xa0 = *(const f4_t*)&xr[0][ib * 8];
        f4_t xa1 = *(const f4_t*)&xr[0][ib * 8 + 4];
        f4_t xb0 = *(const f4_t*)&xr[1][ib * 8];
        f4_t xb1 = *(const f4_t*)&xr[1][ib * 8 + 4];
        zA = fmaf(lo.x, xa0.x, zA); zA = fmaf(lo.y, xa0.y, zA);
        zA = fmaf(lo.z, xa0.z, zA); zA = fmaf(lo.w, xa0.w, zA);
        zA = fmaf(hi.x, xa1.x, zA); zA = fmaf(hi.y, xa1.y, zA);
        zA = fmaf(hi.z, xa1.z, zA); zA = fmaf(hi.w, xa1.w, zA);
        zB = fmaf(lo.x, xb0.x, zB); zB = fmaf(lo.y, xb0.y, zB);
        zB = fmaf(lo.z, xb0.z, zB); zB = fmaf(lo.w, xb0.w, zB);
        zB = fmaf(hi.x, xb1.x, zB); zB = fmaf(hi.y, xb1.y, zB);
        zB = fmaf(hi.z, xb1.z, zB); zB = fmaf(hi.w, xb1.w, zB);
        if (ib < 4) {
          f4_t qa0 = *(const f4_t*)&xr[0][Nn + ib * 8];
          f4_t qa1 = *(const f4_t*)&xr[0][Nn + ib * 8 + 4];
          f4_t qb0 = *(const f4_t*)&xr[1][Nn + ib * 8];
          f4_t qb1 = *(const f4_t*)&xr[1][Nn + ib * 8 + 4];
          rA = fmaf(lo.x, qa0.x, rA); rA = fmaf(lo.y, qa0.y, rA);
          rA = fmaf(lo.z, qa0.z, rA); rA = fmaf(lo.w, qa0.w, rA);
          rA = fmaf(hi.x, qa1.x, rA); rA = fmaf(hi.y, qa1.y, rA);
          rA = fmaf(hi.z, qa1.z, rA); rA = fmaf(hi.w, qa1.w, rA);
          rB = fmaf(lo.x, qb0.x, rB); rB = fmaf(lo.y, qb0.y, rB);
          rB = fmaf(lo.z, qb0.z, rB); rB = fmaf(lo.w, qb0.w, rB);
          rB = fmaf(hi.x, qb1.x, rB); rB = fmaf(hi.y, qb1.y, rB);
          rB = fmaf(hi.z, qb1.z, rB); rB = fmaf(hi.w, qb1.w, rB);
        }
      }
      float f0, f1, f2;
      act012(net, zA, f0, f1, f2);
      Vb[0 * MS + t] = f2bf(f0);            // h1_s0
      Vb[2 * MS + t] = f2bf(f1 * rA);       // u_s0
      act1s[t] = f2bf(f1); d2as[t] = f2bf(f2); rb2[t] = f2bf(rA);
      act012(net, zB, f0, f1, f2);
      Vb[1 * MS + t] = f2bf(f0);            // h1_s1
      Vb[3 * MS + t] = f2bf(f1 * rB);       // u_s1
      act1s[Hh + t] = f2bf(f1); d2as[Hh + t] = f2bf(f2); rb2[Hh + t] = f2bf(rB);
      #pragma unroll
      for (int r = 4; r < 16; ++r) Vb[r * MS + t] = 0;
    }
    __syncthreads();

    // ===== P1b: stage 64 T A-rows: megaA[sm*32+m][k] = act1[sm][k]*W1bot[m][k] =====
    {
      int m2 = t >> 2, smc = m2 >> 5, m = m2 & 31;
      #pragma unroll
      for (int kbi = 0; kbi < 2; ++kbi) {
        int kb = (t & 3) * 2 + kbi;
        int base = ((m >> 4) * 8 + kb) * 512 + (m & 15) * 8;
        #pragma unroll
        for (int q2 = 0; q2 < 4; ++q2) {
          bf8_t w8 = *(const bf8_t*)&w1f[base + q2 * 128];
          f4_t lo, hi; bf8_to_f(w8, lo, hi);
          int k0 = kb * 32 + q2 * 8;
          bf8_t a8 = *(const bf8_t*)&act1s[smc * Hh + k0];
          f4_t alo, ahi; bf8_to_f(a8, alo, ahi);
          *(bf8_t*)&megaA[m2 * MS + k0] = pack8(lo * alo, hi * ahi);
        }
      }
    }
    __syncthreads();

    // ===== megapass: M=80 (4 T-tiles + vec tile) x N=256, K=256 =====
    {
      f4_t accT[4][4], accv[4];
      #pragma unroll
      for (int rt = 0; rt < 4; ++rt)
        #pragma unroll
        for (int j = 0; j < 4; ++j) accT[rt][j] = (f4_t){0.f,0.f,0.f,0.f};
      #pragma unroll
      for (int j = 0; j < 4; ++j) accv[j] = (f4_t){0.f,0.f,0.f,0.f};
      for (int kb = 0; kb < 8; ++kb) {
        int kk = kb * 32 + q * 8;
        bf8_t a0 = *(const bf8_t*)&megaA[(ln16) * MS + kk];
        bf8_t a1 = *(const bf8_t*)&megaA[(16 + ln16) * MS + kk];
        bf8_t a2 = *(const bf8_t*)&megaA[(32 + ln16) * MS + kk];
        bf8_t a3 = *(const bf8_t*)&megaA[(48 + ln16) * MS + kk];
        bf8_t av = *(const bf8_t*)&Vb[ln16 * MS + kk];
        #pragma unroll
        for (int j = 0; j < 4; ++j) {
          bf8_t bv = *(const bf8_t*)&w4[((j * 4 + w) * 16 + ln16) * Hh + kk];  // j/w swapped
          accT[0][j] = __builtin_amdgcn_mfma_f32_16x16x32_bf16(a0, bv, accT[0][j], 0, 0, 0);
          accT[1][j] = __builtin_amdgcn_mfma_f32_16x16x32_bf16(a1, bv, accT[1][j], 0, 0, 0);
          accT[2][j] = __builtin_amdgcn_mfma_f32_16x16x32_bf16(a2, bv, accT[2][j], 0, 0, 0);
          accT[3][j] = __builtin_amdgcn_mfma_f32_16x16x32_bf16(a3, bv, accT[3][j], 0, 0, 0);
          accv[j]    = __builtin_amdgcn_mfma_f32_16x16x32_bf16(av, bv, accv[j], 0, 0, 0);
        }
      }
      __syncthreads();   // all megaA reads done -> safe to overwrite with T
      #pragma unroll
      for (int rt = 0; rt < 4; ++rt)
        #pragma unroll
        for (int j = 0; j < 4; ++j) {
          int col = (j * 4 + w) * 16 + ln16;   // j/w swapped: 4-way instead of 16-way bank conflict
          int rowb = rt * 16 + q * 4;
          megaA[(rowb + 0) * MS + col] = f2bf(accT[rt][j][0]);
          megaA[(rowb + 1) * MS + col] = f2bf(accT[rt][j][1]);
          megaA[(rowb + 2) * MS + col] = f2bf(accT[rt][j][2]);
          megaA[(rowb + 3) * MS + col] = f2bf(accT[rt][j][3]);
        }
      if (q == 0) {
        #pragma unroll
        for (int j = 0; j < 4; ++j) {
          int col = (j * 4 + w) * 16 + ln16;
          buf1[0][col] = accv[j][0];          // z2pre_s0
          buf1[1][col] = accv[j][1];          // z2pre_s1
          tb2[col] = f2bf(accv[j][2]);        // t_s0
          tb2[Hh + col] = f2bf(accv[j][3]);   // t_s1
        }
      }
    }
    __syncthreads();

    // ===== VALU2: s2 -> Vb rows 0-1, bco, twv =====
    {
      float b2t = b2[t], w3t = W3[t];
      float g1, g2;
      act12(net, buf1[0][t] + b2t, g1, g2);
      Vb[0 * MS + t] = f2bf(w3t * g1);
      bco2[t] = f2bf(w3t * g2);
      tb2[t] = f2bf(w3t * g2 * bf2f(tb2[t]));
      act12(net, buf1[1][t] + b2t, g1, g2);
      Vb[1 * MS + t] = f2bf(w3t * g1);
      bco2[Hh + t] = f2bf(w3t * g2);
      tb2[Hh + t] = f2bf(w3t * g2 * bf2f(tb2[Hh + t]));
      Vb[2 * MS + t] = 0; Vb[3 * MS + t] = 0;
    }
    __syncthreads();

    // ===== SYRK-T (both) + Bq2 extra-col + pass2 (v GEMM) =====
    {
      for (int jb = 0; jb < 8; ++jb) {
        int jbase = jb * 32 + q * 8;
        bf8_t bcA8 = *(const bf8_t*)&bco2[jbase];
        bf8_t bcB8 = *(const bf8_t*)&bco2[Hh + jbase];
        f4_t bA0, bA1, bB0, bB1;
        bf8_to_f(bcA8, bA0, bA1); bf8_to_f(bcB8, bB0, bB1);
        bf8_t ta0 = *(const bf8_t*)&megaA[(mtS * 16 + ln16) * MS + jbase];
        bf8_t tb0 = *(const bf8_t*)&megaA[(ntS * 16 + ln16) * MS + jbase];
        bf8_t ta1 = *(const bf8_t*)&megaA[(32 + mtS * 16 + ln16) * MS + jbase];
        bf8_t tb1 = *(const bf8_t*)&megaA[(32 + ntS * 16 + ln16) * MS + jbase];
        f4_t lo, hi;
        bf8_to_f(ta0, lo, hi);
        bf8_t afr0 = pack8(lo * bA0, hi * bA1);
        sacc0 = __builtin_amdgcn_mfma_f32_16x16x32_bf16(afr0, tb0, sacc0, 0, 0, 0);
        bf8_to_f(ta1, lo, hi);
        bf8_t afr1 = pack8(lo * bB0, hi * bB1);
        sacc1 = __builtin_amdgcn_mfma_f32_16x16x32_bf16(afr1, tb1, sacc1, 0, 0, 0);
        bf8_t tw8 = *(const bf8_t*)&tb2[esT * Hh + jbase];
        bf8_t btw = (ln16 == 0) ? tw8 : z8;
        bq2acc = __builtin_amdgcn_mfma_f32_16x16x32_bf16(esT ? tb1 : tb0, btw, bq2acc, 0, 0, 0);
      }
      f4_t p2[4];
      #pragma unroll
      for (int j = 0; j < 4; ++j) p2[j] = (f4_t){0.f,0.f,0.f,0.f};
      for (int kb = 0; kb < 8; ++kb) {
        int kk = kb * 32 + q * 8;
        bf8_t av = *(const bf8_t*)&Vb[ln16 * MS + kk];
        #pragma unroll
        for (int j = 0; j < 4; ++j) {
          bf8_t bv = *(const bf8_t*)&w5[((w * 4 + j) * 16 + ln16) * Hh + kk];
          p2[j] = __builtin_amdgcn_mfma_f32_16x16x32_bf16(av, bv, p2[j], 0, 0, 0);
        }
      }
      if (q == 0) {
        #pragma unroll
        for (int j = 0; j < 4; ++j) {
          int col = (w * 4 + j) * 16 + ln16;
          buf1[0][col] = p2[j][0];   // v_s0
          buf1[1][col] = p2[j][1];   // v_s1
        }
      }
    }
    __syncthreads();

    // ===== VALU3: jac accumulate (regs) + stage SYRK-W rows into megaA =====
    {
      const float* wt = W1 + rg * Hh + kc;
      #pragma unroll
      for (int k8 = 0; k8 < 4; ++k8) {
        int kk = kc + k8 * 8;
        f4_t w0 = *(const f4_t*)&wt[k8 * 8];
        f4_t w1v = *(const f4_t*)&wt[k8 * 8 + 4];
        bf8_t aA8 = *(const bf8_t*)&act1s[kk];
        bf8_t aB8 = *(const bf8_t*)&act1s[Hh + kk];
        f4_t aA0, aA1, aB0, aB1;
        bf8_to_f(aA8, aA0, aA1); bf8_to_f(aB8, aB0, aB1);
        f4_t vA0 = *(const f4_t*)&buf1[0][kk];
        f4_t vA1 = *(const f4_t*)&buf1[0][kk + 4];
        f4_t vB0 = *(const f4_t*)&buf1[1][kk];
        f4_t vB1 = *(const f4_t*)&buf1[1][kk + 4];
        jA = fmaf(w0.x, aA0.x * vA0.x, jA); jA = fmaf(w0.y, aA0.y * vA0.y, jA);
        jA = fmaf(w0.z, aA0.z * vA0.z, jA); jA = fmaf(w0.w, aA0.w * vA0.w, jA);
        jA = fmaf(w1v.x, aA1.x * vA1.x, jA); jA = fmaf(w1v.y, aA1.y * vA1.y, jA);
        jA = fmaf(w1v.z, aA1.z * vA1.z, jA); jA = fmaf(w1v.w, aA1.w * vA1.w, jA);
        jB = fmaf(w0.x, aB0.x * vB0.x, jB); jB = fmaf(w0.y, aB0.y * vB0.y, jB);
        jB = fmaf(w0.z, aB0.z * vB0.z, jB); jB = fmaf(w0.w, aB0.w * vB0.w, jB);
        jB = fmaf(w1v.x, aB1.x * vB1.x, jB); jB = fmaf(w1v.y, aB1.y * vB1.y, jB);
        jB = fmaf(w1v.z, aB1.z * vB1.z, jB); jB = fmaf(w1v.w, aB1.w * vB1.w, jB);
      }
      int m2 = t >> 2, smc = m2 >> 5, m = m2 & 31;
      #pragma unroll
      for (int kbi = 0; kbi < 2; ++kbi) {
        int kb = (t & 3) * 2 + kbi;
        int base = ((m >> 4) * 8 + kb) * 512 + (m & 15) * 8;
        #pragma unroll
        for (int q2 = 0; q2 < 4; ++q2) {
          bf8_t w8 = *(const bf8_t*)&w1f[base + q2 * 128];
          f4_t lo, hi; bf8_to_f(w8, lo, hi);
          int k0 = kb * 32 + q2 * 8;
          bf8_t d8 = *(const bf8_t*)&d2as[smc * Hh + k0];
          f4_t dlo, dhi; bf8_to_f(d8, dlo, dhi);
          f4_t vv0 = *(const f4_t*)&buf1[smc][k0];
          f4_t vv1 = *(const f4_t*)&buf1[smc][k0 + 4];
          *(bf8_t*)&megaA[m2 * MS + k0] = pack8(lo * (dlo * vv0), hi * (dhi * vv1));
        }
      }
    }
    __syncthreads();

    // ===== SYRK-W (both) + Bq1 extra-col =====
    for (int kb = 0; kb < 8; ++kb) {
      int kk = kb * 32 + q * 8;
      bf8_t bfr = *(const bf8_t*)&w1f[(ntS * 8 + kb) * 512 + lane * 8];
      bf8_t a0 = *(const bf8_t*)&megaA[(mtS * 16 + ln16) * MS + kk];
      bf8_t a1 = *(const bf8_t*)&megaA[(32 + mtS * 16 + ln16) * MS + kk];
      sacc0 = __builtin_amdgcn_mfma_f32_16x16x32_bf16(a0, bfr, sacc0, 0, 0, 0);
      sacc1 = __builtin_amdgcn_mfma_f32_16x16x32_bf16(a1, bfr, sacc1, 0, 0, 0);
      bf8_t rb8 = *(const bf8_t*)&rb2[esW * Hh + kk];
      bf8_t brf = (ln16 == 0) ? rb8 : z8;
      bq1acc = __builtin_amdgcn_mfma_f32_16x16x32_bf16(esW ? a1 : a0, brf, bq1acc, 0, 0, 0);
    }
    __syncthreads();
  }

  // ===== dumps: Bq1/Bq2/jac =====
  if (ln16 == 0) {
    #pragma unroll
    for (int r = 0; r < 4; ++r) {
      Bq2v[esT * Nn + ntS * 16 + q * 4 + r] = bq2acc[r];
      Bq1v[esW * Nn + mtS * 16 + q * 4 + r] = bq1acc[r];
    }
  }
  {
    jA += __shfl_xor(jA, 1, 64); jA += __shfl_xor(jA, 2, 64); jA += __shfl_xor(jA, 4, 64);
    jB += __shfl_xor(jB, 1, 64); jB += __shfl_xor(jB, 2, 64); jB += __shfl_xor(jB, 4, 64);
    if ((lane & 7) == 0) { jacv[rg] = jA; jacv[Nn + rg] = jB; }
  }
  __syncthreads();
  {
    int col = ntS * 16 + ln16;
    int rowb = mtS * 16 + q * 4;
    #pragma unroll
    for (int r = 0; r < 4; ++r) {
      AugF[(rowb + r) * AS + col] = sacc0[r];
      AugF[(Nn + rowb + r) * AS + col] = sacc1[r];
    }
  }
  __syncthreads();
  if (t < 64) {
    int smp = t >> 5, r = t & 31;
    AugF[(smp * Nn + r) * AS + r] += 2.0f;
    AugF[(smp * Nn + r) * AS + Nn] = jacv[smp * Nn + r] - Bq1v[smp * Nn + r] - Bq2v[smp * Nn + r];
  }
  __syncthreads();

  // ===== register Gauss-Jordan, no pivot (A = 2I + small) =====
  if (w < 2 && lane < 32) {
    int smp = w, r = lane;
    float a[Nn + 1];
    #pragma unroll
    for (int c = 0; c <= Nn; ++c) a[c] = AugF[(smp * Nn + r) * AS + c];
    float mydiag = 1.f;
    #pragma unroll
    for (int st = 0; st < Nn; ++st) {
      float pd = __shfl(a[st], st, 64);
      mydiag = (r == st) ? pd : mydiag;
      float f = a[st] / pd;
      bool self = (r == st);
      #pragma unroll
      for (int c = st + 1; c <= Nn; ++c) {
        float pc = __shfl(a[c], st, 64);
        if (!self) a[c] = fmaf(-f, pc, a[c]);
      }
    }
    out[(s0 + smp) * Dd + r] = xr[smp][Nn + r];          // qdot
    out[(s0 + smp) * Dd + Nn + r] = a[Nn] / mydiag;      // qdd
  }
}

extern "C" void kernel_launch(void* const* d_in, const int* in_sizes, int n_in,
                              void* d_out, int out_size, void* d_ws, size_t ws_size,
                              hipStream_t stream) {
  const float* x   = (const float*)d_in[0];
  const float* mW1 = (const float*)d_in[1];
  const float* mb1 = (const float*)d_in[2];
  const float* mW2 = (const float*)d_in[3];
  const float* mb2 = (const float*)d_in[4];
  const float* mW3 = (const float*)d_in[5];
  const float* qW1 = (const float*)d_in[6];
  const float* qb1 = (const float*)d_in[7];
  const float* qW2 = (const float*)d_in[8];
  const float* qb2 = (const float*)d_in[9];
  const float* qW3 = (const float*)d_in[10];

  short* ws4 = (short*)d_ws;                          // 256 KB
  short* ws5 = (short*)((char*)d_ws + 262144);        // 256 KB
  short* ws1 = (short*)((char*)d_ws + 524288);        // 32 KB
  short* ws6 = (short*)((char*)d_ws + 557056);        // 64 KB

  pack_kernel<<<dim3(1216), dim3(256), 0, stream>>>(mW1, mW2, qW1, qW2, ws4, ws5, ws1, ws6);

  const int B = in_sizes[0] / Dd;   // 4096
  lnn_kernel<<<dim3(B / 2), dim3(256), 0, stream>>>(
      x, mW1, mb1, mW2, mb2, mW3, qW1, qb1, qW2, qb2, qW3, ws4, ws5, ws1, ws6, (float*)d_out);
}

// Round 12
// 301.585 us; speedup vs baseline: 1.2324x; 1.2324x over previous
//
#include <hip/hip_runtime.h>
#include <math.h>

#define Hh 256
#define Dd 64
#define Nn 32
#define MS 264   // stride (shorts): 528 B/row
#define AS 33    // Aug stride (floats)

typedef __attribute__((ext_vector_type(8))) short bf8_t;
typedef __attribute__((ext_vector_type(4))) float f4_t;

__device__ __forceinline__ short f2bf(float f) {
  union { float f; unsigned u; } v; v.f = f;
  unsigned r = v.u + 0x7FFFu + ((v.u >> 16) & 1u);
  return (short)(r >> 16);
}
__device__ __forceinline__ float bf2f(short s) {
  union { unsigned u; float f; } v;
  v.u = ((unsigned)(unsigned short)s) << 16;
  return v.f;
}
__device__ __forceinline__ bf8_t pack8(f4_t lo, f4_t hi) {
  bf8_t r;
  r[0] = f2bf(lo.x); r[1] = f2bf(lo.y); r[2] = f2bf(lo.z); r[3] = f2bf(lo.w);
  r[4] = f2bf(hi.x); r[5] = f2bf(hi.y); r[6] = f2bf(hi.z); r[7] = f2bf(hi.w);
  return r;
}
__device__ __forceinline__ void bf8_to_f(bf8_t v, f4_t& lo, f4_t& hi) {
  lo.x = bf2f(v[0]); lo.y = bf2f(v[1]); lo.z = bf2f(v[2]); lo.w = bf2f(v[3]);
  hi.x = bf2f(v[4]); hi.y = bf2f(v[5]); hi.z = bf2f(v[6]); hi.w = bf2f(v[7]);
}
__device__ __forceinline__ void act012(int net, float z, float& f0, float& f1, float& f2) {
  if (net == 0) {
    float e = __expf(-z);
    float sg = 1.f / (1.f + e);
    f0 = (z > 20.f) ? z : __logf(1.f + __expf(z));
    f1 = sg; f2 = sg * (1.f - sg);
  } else {
    float az = fabsf(z);
    float e = __expf(-az);
    float th = (1.f - e) / (1.f + e);
    th = (z < 0.f) ? -th : th;
    float sech2 = 1.f - th * th;
    f0 = z * th;
    f1 = th + 0.5f * z * sech2;
    f2 = sech2 * (1.f - 0.5f * z * th);
  }
}
__device__ __forceinline__ void act12(int net, float z, float& g1, float& g2) {
  if (net == 0) {
    float e = __expf(-z);
    float sg = 1.f / (1.f + e);
    g1 = sg; g2 = sg * (1.f - sg);
  } else {
    float az = fabsf(z);
    float e = __expf(-az);
    float th = (1.f - e) / (1.f + e);
    th = (z < 0.f) ? -th : th;
    float sech2 = 1.f - th * th;
    g1 = th + 0.5f * z * sech2;
    g2 = sech2 * (1.f - 0.5f * z * th);
  }
}

// ---- pre-pack (reads coalesced, writes scattered) ----
// ws4[net*65536 + c*256 + k]             = bf16(W2[k][c])
// ws5[net*65536 + k*256 + j]             = bf16(W2[k][j])
// ws1[((net*2+mt)*8+kb)*512 + lane*8+jj] = bf16(W1[32+mt*16+(lane&15)][kb*32+(lane>>4)*8+jj])
// ws6[net*16384 + t*64 + i]              = bf16(W1[i][t])
__global__ void pack_kernel(const float* __restrict__ mW1, const float* __restrict__ mW2,
                            const float* __restrict__ qW1, const float* __restrict__ qW2,
                            short* __restrict__ ws4, short* __restrict__ ws5,
                            short* __restrict__ ws1, short* __restrict__ ws6) {
  int id = blockIdx.x * 256 + threadIdx.x;
  if (id < 131072) {
    int net = id >> 16, r = id & 65535;
    const float* W2 = net ? qW2 : mW2;
    int k = r >> 8, c = r & 255;               // read W2[k*256+c] coalesced (c fast)
    ws4[net * 65536 + c * 256 + k] = f2bf(W2[k * Hh + c]);
  } else if (id < 262144) {
    int id2 = id - 131072;
    int net = id2 >> 16;
    const float* W2 = net ? qW2 : mW2;
    int k = (id2 >> 8) & 255, j = id2 & 255;   // identity: coalesced both sides
    ws5[id2] = f2bf(W2[k * Hh + j]);
  } else if (id < 278528) {
    int id2 = id - 262144;
    int net = id2 >> 13, r = id2 & 8191;
    const float* W1 = net ? qW1 : mW1;
    int mt = r >> 12, kb = (r >> 9) & 7, lane = (r >> 3) & 63, jj = r & 7;
    int m = Nn + mt * 16 + (lane & 15);
    int k = kb * 32 + (lane >> 4) * 8 + jj;
    ws1[id2] = f2bf(W1[m * Hh + k]);
  } else if (id < 311296) {
    int id3 = id - 278528;
    int net = id3 >> 14, r = id3 & 16383;
    const float* W1 = net ? qW1 : mW1;
    int i = r >> 8, tc = r & 255;              // read W1[i*256+tc] coalesced (tc fast)
    ws6[net * 16384 + tc * 64 + i] = f2bf(W1[i * Hh + tc]);
  }
}

__global__ __launch_bounds__(256, 2) void lnn_kernel(
    const float* __restrict__ x,
    const float* __restrict__ mW1, const float* __restrict__ mb1,
    const float* __restrict__ mW2, const float* __restrict__ mb2,
    const float* __restrict__ mW3,
    const float* __restrict__ qW1, const float* __restrict__ qb1,
    const float* __restrict__ qW2, const float* __restrict__ qb2,
    const float* __restrict__ qW3,
    const short* __restrict__ ws4, const short* __restrict__ ws5,
    const short* __restrict__ ws1, const short* __restrict__ ws6,
    float* __restrict__ out)
{
  const int t = threadIdx.x;
  const int w = t >> 6, lane = t & 63, q = lane >> 4, ln16 = lane & 15;
  const int s0 = blockIdx.x * 2;

  __shared__ __align__(16) short megaA[64 * MS];      // staged A-tiles; T written back in place
  __shared__ __align__(16) short Vb[20 * MS];         // vec tiles (rows net*4+0..3); Aug alias at end
  __shared__ __align__(16) float xr[2][Dd];
  __shared__ __align__(16) short act1s[4 * Hh], d2as[4 * Hh], rb2[4 * Hh];  // [net][smp][256]
  __shared__ __align__(16) short bco2[2 * Hh], tb2[2 * Hh];
  __shared__ __align__(16) float buf1[2][Hh];         // z2pre -> v
  __shared__ float jacv[2 * Nn], Bq1v[2 * Nn], Bq2v[2 * Nn];
  float* AugF = (float*)Vb;

  if (t < 128) ((float*)xr)[t] = x[s0 * Dd + t];
  __syncthreads();

  f4_t sacc0 = {0.f,0.f,0.f,0.f}, sacc1 = {0.f,0.f,0.f,0.f};
  f4_t bq1acc = {0.f,0.f,0.f,0.f}, bq2acc = {0.f,0.f,0.f,0.f};
  float jA = 0.f, jB = 0.f;
  const int mtS = w >> 1, ntS = w & 1;
  const int esT = w >> 1;
  const int esW = w & 1;
  const int rg = w * 8 + (lane >> 3);
  const int kc = (lane & 7) * 32;
  const bf8_t z8 = {0,0,0,0,0,0,0,0};

  // ===== merged P1a: z1 + rbuf + act derivatives for BOTH nets =====
  for (int net = 0; net < 2; ++net) {
    const float* b1 = net ? qb1 : mb1;
    const short* w6 = ws6 + net * 16384 + t * 64;
    float b1t = b1[t];
    float zA = b1t, zB = b1t, rA = 0.f, rB = 0.f;
    #pragma unroll
    for (int ib = 0; ib < 8; ++ib) {
      bf8_t w8 = *(const bf8_t*)&w6[ib * 8];
      f4_t lo, hi; bf8_to_f(w8, lo, hi);
      f4_t xa0 = *(const f4_t*)&xr[0][ib * 8];
      f4_t xa1 = *(const f4_t*)&xr[0][ib * 8 + 4];
      f4_t xb0 = *(const f4_t*)&xr[1][ib * 8];
      f4_t xb1 = *(const f4_t*)&xr[1][ib * 8 + 4];
      zA = fmaf(lo.x, xa0.x, zA); zA = fmaf(lo.y, xa0.y, zA);
      zA = fmaf(lo.z, xa0.z, zA); zA = fmaf(lo.w, xa0.w, zA);
      zA = fmaf(hi.x, xa1.x, zA); zA = fmaf(hi.y, xa1.y, zA);
      zA = fmaf(hi.z, xa1.z, zA); zA = fmaf(hi.w, xa1.w, zA);
      zB = fmaf(lo.x, xb0.x, zB); zB = fmaf(lo.y, xb0.y, zB);
      zB = fmaf(lo.z, xb0.z, zB); zB = fmaf(lo.w, xb0.w, zB);
      zB = fmaf(hi.x, xb1.x, zB); zB = fmaf(hi.y, xb1.y, zB);
      zB = fmaf(hi.z, xb1.z, zB); zB = fmaf(hi.w, xb1.w, zB);
      if (ib < 4) {
        f4_t qa0 = *(const f4_t*)&xr[0][Nn + ib * 8];
        f4_t qa1 = *(const f4_t*)&xr[0][Nn + ib * 8 + 4];
        f4_t qb0 = *(const f4_t*)&xr[1][Nn + ib * 8];
        f4_t qb1 = *(const f4_t*)&xr[1][Nn + ib * 8 + 4];
        rA = fmaf(lo.x, qa0.x, rA); rA = fmaf(lo.y, qa0.y, rA);
        rA = fmaf(lo.z, qa0.z, rA); rA = fmaf(lo.w, qa0.w, rA);
        rA = fmaf(hi.x, qa1.x, rA); rA = fmaf(hi.y, qa1.y, rA);
        rA = fmaf(hi.z, qa1.z, rA); rA = fmaf(hi.w, qa1.w, rA);
        rB = fmaf(lo.x, qb0.x, rB); rB = fmaf(lo.y, qb0.y, rB);
        rB = fmaf(lo.z, qb0.z, rB); rB = fmaf(lo.w, qb0.w, rB);
        rB = fmaf(hi.x, qb1.x, rB); rB = fmaf(hi.y, qb1.y, rB);
        rB = fmaf(hi.z, qb1.z, rB); rB = fmaf(hi.w, qb1.w, rB);
      }
    }
    float f0, f1, f2;
    act012(net, zA, f0, f1, f2);
    Vb[(net * 4 + 0) * MS + t] = f2bf(f0);        // h1_s0
    Vb[(net * 4 + 2) * MS + t] = f2bf(f1 * rA);   // u_s0
    act1s[net * 512 + t] = f2bf(f1); d2as[net * 512 + t] = f2bf(f2); rb2[net * 512 + t] = f2bf(rA);
    act012(net, zB, f0, f1, f2);
    Vb[(net * 4 + 1) * MS + t] = f2bf(f0);        // h1_s1
    Vb[(net * 4 + 3) * MS + t] = f2bf(f1 * rB);   // u_s1
    act1s[net * 512 + Hh + t] = f2bf(f1); d2as[net * 512 + Hh + t] = f2bf(f2); rb2[net * 512 + Hh + t] = f2bf(rB);
  }
  __syncthreads();

  for (int net = 0; net < 2; ++net) {
    const float* W1 = net ? qW1 : mW1;
    const float* b2 = net ? qb2 : mb2;
    const float* W3 = net ? qW3 : mW3;
    const short* w4 = ws4 + net * 65536;
    const short* w5 = ws5 + net * 65536;
    const short* w1f = ws1 + net * 8192;
    const int no = net * 512;   // per-net aux offset

    // ===== P1b: stage 64 T A-rows: megaA[sm*32+m][k] = act1[sm][k]*W1bot[m][k] =====
    {
      int m2 = t >> 2, smc = m2 >> 5, m = m2 & 31;
      #pragma unroll
      for (int kbi = 0; kbi < 2; ++kbi) {
        int kb = (t & 3) * 2 + kbi;
        int base = ((m >> 4) * 8 + kb) * 512 + (m & 15) * 8;
        #pragma unroll
        for (int q2 = 0; q2 < 4; ++q2) {
          bf8_t w8 = *(const bf8_t*)&w1f[base + q2 * 128];
          f4_t lo, hi; bf8_to_f(w8, lo, hi);
          int k0 = kb * 32 + q2 * 8;
          bf8_t a8 = *(const bf8_t*)&act1s[no + smc * Hh + k0];
          f4_t alo, ahi; bf8_to_f(a8, alo, ahi);
          *(bf8_t*)&megaA[m2 * MS + k0] = pack8(lo * alo, hi * ahi);
        }
      }
    }
    __syncthreads();

    // ===== megapass: M=80 (4 T-tiles + vec tile) x N=256, K=256 =====
    {
      f4_t accT[4][4], accv[4];
      #pragma unroll
      for (int rt = 0; rt < 4; ++rt)
        #pragma unroll
        for (int j = 0; j < 4; ++j) accT[rt][j] = (f4_t){0.f,0.f,0.f,0.f};
      #pragma unroll
      for (int j = 0; j < 4; ++j) accv[j] = (f4_t){0.f,0.f,0.f,0.f};
      for (int kb = 0; kb < 8; ++kb) {
        int kk = kb * 32 + q * 8;
        bf8_t a0 = *(const bf8_t*)&megaA[(ln16) * MS + kk];
        bf8_t a1 = *(const bf8_t*)&megaA[(16 + ln16) * MS + kk];
        bf8_t a2 = *(const bf8_t*)&megaA[(32 + ln16) * MS + kk];
        bf8_t a3 = *(const bf8_t*)&megaA[(48 + ln16) * MS + kk];
        bf8_t av = *(const bf8_t*)&Vb[(net * 4 + ln16) * MS + kk];
        #pragma unroll
        for (int j = 0; j < 4; ++j) {
          bf8_t bv = *(const bf8_t*)&w4[((w * 4 + j) * 16 + ln16) * Hh + kk];
          accT[0][j] = __builtin_amdgcn_mfma_f32_16x16x32_bf16(a0, bv, accT[0][j], 0, 0, 0);
          accT[1][j] = __builtin_amdgcn_mfma_f32_16x16x32_bf16(a1, bv, accT[1][j], 0, 0, 0);
          accT[2][j] = __builtin_amdgcn_mfma_f32_16x16x32_bf16(a2, bv, accT[2][j], 0, 0, 0);
          accT[3][j] = __builtin_amdgcn_mfma_f32_16x16x32_bf16(a3, bv, accT[3][j], 0, 0, 0);
          accv[j]    = __builtin_amdgcn_mfma_f32_16x16x32_bf16(av, bv, accv[j], 0, 0, 0);
        }
      }
      __syncthreads();   // all megaA reads done -> safe to overwrite with T
      #pragma unroll
      for (int rt = 0; rt < 4; ++rt)
        #pragma unroll
        for (int j = 0; j < 4; ++j) {
          int col = (w * 4 + j) * 16 + ln16;
          int rowb = rt * 16 + q * 4;
          megaA[(rowb + 0) * MS + col] = f2bf(accT[rt][j][0]);
          megaA[(rowb + 1) * MS + col] = f2bf(accT[rt][j][1]);
          megaA[(rowb + 2) * MS + col] = f2bf(accT[rt][j][2]);
          megaA[(rowb + 3) * MS + col] = f2bf(accT[rt][j][3]);
        }
      if (q == 0) {
        #pragma unroll
        for (int j = 0; j < 4; ++j) {
          int col = (w * 4 + j) * 16 + ln16;
          buf1[0][col] = accv[j][0];          // z2pre_s0
          buf1[1][col] = accv[j][1];          // z2pre_s1
          tb2[col] = f2bf(accv[j][2]);        // t_s0
          tb2[Hh + col] = f2bf(accv[j][3]);   // t_s1
        }
      }
    }
    __syncthreads();

    // ===== VALU2: s2 -> Vb rows net*4+0/1, bco, twv =====
    {
      float b2t = b2[t], w3t = W3[t];
      float g1, g2;
      act12(net, buf1[0][t] + b2t, g1, g2);
      Vb[(net * 4 + 0) * MS + t] = f2bf(w3t * g1);
      bco2[t] = f2bf(w3t * g2);
      tb2[t] = f2bf(w3t * g2 * bf2f(tb2[t]));
      act12(net, buf1[1][t] + b2t, g1, g2);
      Vb[(net * 4 + 1) * MS + t] = f2bf(w3t * g1);
      bco2[Hh + t] = f2bf(w3t * g2);
      tb2[Hh + t] = f2bf(w3t * g2 * bf2f(tb2[Hh + t]));
    }
    __syncthreads();

    // ===== SYRK-T (both) + Bq2 extra-col + pass2 (v GEMM) =====
    {
      for (int jb = 0; jb < 8; ++jb) {
        int jbase = jb * 32 + q * 8;
        bf8_t bcA8 = *(const bf8_t*)&bco2[jbase];
        bf8_t bcB8 = *(const bf8_t*)&bco2[Hh + jbase];
        f4_t bA0, bA1, bB0, bB1;
        bf8_to_f(bcA8, bA0, bA1); bf8_to_f(bcB8, bB0, bB1);
        bf8_t ta0 = *(const bf8_t*)&megaA[(mtS * 16 + ln16) * MS + jbase];
        bf8_t tb0 = *(const bf8_t*)&megaA[(ntS * 16 + ln16) * MS + jbase];
        bf8_t ta1 = *(const bf8_t*)&megaA[(32 + mtS * 16 + ln16) * MS + jbase];
        bf8_t tb1 = *(const bf8_t*)&megaA[(32 + ntS * 16 + ln16) * MS + jbase];
        f4_t lo, hi;
        bf8_to_f(ta0, lo, hi);
        bf8_t afr0 = pack8(lo * bA0, hi * bA1);
        sacc0 = __builtin_amdgcn_mfma_f32_16x16x32_bf16(afr0, tb0, sacc0, 0, 0, 0);
        bf8_to_f(ta1, lo, hi);
        bf8_t afr1 = pack8(lo * bB0, hi * bB1);
        sacc1 = __builtin_amdgcn_mfma_f32_16x16x32_bf16(afr1, tb1, sacc1, 0, 0, 0);
        bf8_t tw8 = *(const bf8_t*)&tb2[esT * Hh + jbase];
        bf8_t btw = (ln16 == 0) ? tw8 : z8;
        bq2acc = __builtin_amdgcn_mfma_f32_16x16x32_bf16(esT ? tb1 : tb0, btw, bq2acc, 0, 0, 0);
      }
      f4_t p2[4];
      #pragma unroll
      for (int j = 0; j < 4; ++j) p2[j] = (f4_t){0.f,0.f,0.f,0.f};
      for (int kb = 0; kb < 8; ++kb) {
        int kk = kb * 32 + q * 8;
        bf8_t av = *(const bf8_t*)&Vb[(net * 4 + ln16) * MS + kk];
        #pragma unroll
        for (int j = 0; j < 4; ++j) {
          bf8_t bv = *(const bf8_t*)&w5[((w * 4 + j) * 16 + ln16) * Hh + kk];
          p2[j] = __builtin_amdgcn_mfma_f32_16x16x32_bf16(av, bv, p2[j], 0, 0, 0);
        }
      }
      if (q == 0) {
        #pragma unroll
        for (int j = 0; j < 4; ++j) {
          int col = (w * 4 + j) * 16 + ln16;
          buf1[0][col] = p2[j][0];   // v_s0
          buf1[1][col] = p2[j][1];   // v_s1
        }
      }
    }
    __syncthreads();

    // ===== VALU3: jac accumulate (regs) + stage SYRK-W rows into megaA =====
    {
      const float* wt = W1 + rg * Hh + kc;
      #pragma unroll
      for (int k8 = 0; k8 < 4; ++k8) {
        int kk = kc + k8 * 8;
        f4_t w0 = *(const f4_t*)&wt[k8 * 8];
        f4_t w1v = *(const f4_t*)&wt[k8 * 8 + 4];
        bf8_t aA8 = *(const bf8_t*)&act1s[no + kk];
        bf8_t aB8 = *(const bf8_t*)&act1s[no + Hh + kk];
        f4_t aA0, aA1, aB0, aB1;
        bf8_to_f(aA8, aA0, aA1); bf8_to_f(aB8, aB0, aB1);
        f4_t vA0 = *(const f4_t*)&buf1[0][kk];
        f4_t vA1 = *(const f4_t*)&buf1[0][kk + 4];
        f4_t vB0 = *(const f4_t*)&buf1[1][kk];
        f4_t vB1 = *(const f4_t*)&buf1[1][kk + 4];
        jA = fmaf(w0.x, aA0.x * vA0.x, jA); jA = fmaf(w0.y, aA0.y * vA0.y, jA);
        jA = fmaf(w0.z, aA0.z * vA0.z, jA); jA = fmaf(w0.w, aA0.w * vA0.w, jA);
        jA = fmaf(w1v.x, aA1.x * vA1.x, jA); jA = fmaf(w1v.y, aA1.y * vA1.y, jA);
        jA = fmaf(w1v.z, aA1.z * vA1.z, jA); jA = fmaf(w1v.w, aA1.w * vA1.w, jA);
        jB = fmaf(w0.x, aB0.x * vB0.x, jB); jB = fmaf(w0.y, aB0.y * vB0.y, jB);
        jB = fmaf(w0.z, aB0.z * vB0.z, jB); jB = fmaf(w0.w, aB0.w * vB0.w, jB);
        jB = fmaf(w1v.x, aB1.x * vB1.x, jB); jB = fmaf(w1v.y, aB1.y * vB1.y, jB);
        jB = fmaf(w1v.z, aB1.z * vB1.z, jB); jB = fmaf(w1v.w, aB1.w * vB1.w, jB);
      }
      int m2 = t >> 2, smc = m2 >> 5, m = m2 & 31;
      #pragma unroll
      for (int kbi = 0; kbi < 2; ++kbi) {
        int kb = (t & 3) * 2 + kbi;
        int base = ((m >> 4) * 8 + kb) * 512 + (m & 15) * 8;
        #pragma unroll
        for (int q2 = 0; q2 < 4; ++q2) {
          bf8_t w8 = *(const bf8_t*)&w1f[base + q2 * 128];
          f4_t lo, hi; bf8_to_f(w8, lo, hi);
          int k0 = kb * 32 + q2 * 8;
          bf8_t d8 = *(const bf8_t*)&d2as[no + smc * Hh + k0];
          f4_t dlo, dhi; bf8_to_f(d8, dlo, dhi);
          f4_t vv0 = *(const f4_t*)&buf1[smc][k0];
          f4_t vv1 = *(const f4_t*)&buf1[smc][k0 + 4];
          *(bf8_t*)&megaA[m2 * MS + k0] = pack8(lo * (dlo * vv0), hi * (dhi * vv1));
        }
      }
    }
    __syncthreads();

    // ===== SYRK-W (both) + Bq1 extra-col =====
    for (int kb = 0; kb < 8; ++kb) {
      int kk = kb * 32 + q * 8;
      bf8_t bfr = *(const bf8_t*)&w1f[(ntS * 8 + kb) * 512 + lane * 8];
      bf8_t a0 = *(const bf8_t*)&megaA[(mtS * 16 + ln16) * MS + kk];
      bf8_t a1 = *(const bf8_t*)&megaA[(32 + mtS * 16 + ln16) * MS + kk];
      sacc0 = __builtin_amdgcn_mfma_f32_16x16x32_bf16(a0, bfr, sacc0, 0, 0, 0);
      sacc1 = __builtin_amdgcn_mfma_f32_16x16x32_bf16(a1, bfr, sacc1, 0, 0, 0);
      bf8_t rb8 = *(const bf8_t*)&rb2[no + esW * Hh + kk];
      bf8_t brf = (ln16 == 0) ? rb8 : z8;
      bq1acc = __builtin_amdgcn_mfma_f32_16x16x32_bf16(esW ? a1 : a0, brf, bq1acc, 0, 0, 0);
    }
    __syncthreads();
  }

  // ===== dumps: Bq1/Bq2/jac =====
  if (ln16 == 0) {
    #pragma unroll
    for (int r = 0; r < 4; ++r) {
      Bq2v[esT * Nn + ntS * 16 + q * 4 + r] = bq2acc[r];
      Bq1v[esW * Nn + mtS * 16 + q * 4 + r] = bq1acc[r];
    }
  }
  {
    jA += __shfl_xor(jA, 1, 64); jA += __shfl_xor(jA, 2, 64); jA += __shfl_xor(jA, 4, 64);
    jB += __shfl_xor(jB, 1, 64); jB += __shfl_xor(jB, 2, 64); jB += __shfl_xor(jB, 4, 64);
    if ((lane & 7) == 0) { jacv[rg] = jA; jacv[Nn + rg] = jB; }
  }
  __syncthreads();
  {
    int col = ntS * 16 + ln16;
    int rowb = mtS * 16 + q * 4;
    #pragma unroll
    for (int r = 0; r < 4; ++r) {
      AugF[(rowb + r) * AS + col] = sacc0[r];
      AugF[(Nn + rowb + r) * AS + col] = sacc1[r];
    }
  }
  __syncthreads();
  if (t < 64) {
    int smp = t >> 5, r = t & 31;
    AugF[(smp * Nn + r) * AS + r] += 2.0f;
    AugF[(smp * Nn + r) * AS + Nn] = jacv[smp * Nn + r] - Bq1v[smp * Nn + r] - Bq2v[smp * Nn + r];
  }
  __syncthreads();

  // ===== register Gauss-Jordan, no pivot (A = 2I + small) =====
  if (w < 2 && lane < 32) {
    int smp = w, r = lane;
    float a[Nn + 1];
    #pragma unroll
    for (int c = 0; c <= Nn; ++c) a[c] = AugF[(smp * Nn + r) * AS + c];
    float mydiag = 1.f;
    #pragma unroll
    for (int st = 0; st < Nn; ++st) {
      float pd = __shfl(a[st], st, 64);
      mydiag = (r == st) ? pd : mydiag;
      float f = a[st] / pd;
      bool self = (r == st);
      #pragma unroll
      for (int c = st + 1; c <= Nn; ++c) {
        float pc = __shfl(a[c], st, 64);
        if (!self) a[c] = fmaf(-f, pc, a[c]);
      }
    }
    out[(s0 + smp) * Dd + r] = xr[smp][Nn + r];          // qdot
    out[(s0 + smp) * Dd + Nn + r] = a[Nn] / mydiag;      // qdd
  }
}

extern "C" void kernel_launch(void* const* d_in, const int* in_sizes, int n_in,
                              void* d_out, int out_size, void* d_ws, size_t ws_size,
                              hipStream_t stream) {
  const float* x   = (const float*)d_in[0];
  const float* mW1 = (const float*)d_in[1];
  const float* mb1 = (const float*)d_in[2];
  const float* mW2 = (const float*)d_in[3];
  const float* mb2 = (const float*)d_in[4];
  const float* mW3 = (const float*)d_in[5];
  const float* qW1 = (const float*)d_in[6];
  const float* qb1 = (const float*)d_in[7];
  const float* qW2 = (const float*)d_in[8];
  const float* qb2 = (const float*)d_in[9];
  const float* qW3 = (const float*)d_in[10];

  short* ws4 = (short*)d_ws;                          // 256 KB
  short* ws5 = (short*)((char*)d_ws + 262144);        // 256 KB
  short* ws1 = (short*)((char*)d_ws + 524288);        // 32 KB
  short* ws6 = (short*)((char*)d_ws + 557056);        // 64 KB

  pack_kernel<<<dim3(1216), dim3(256), 0, stream>>>(mW1, mW2, qW1, qW2, ws4, ws5, ws1, ws6);

  const int B = in_sizes[0] / Dd;   // 4096
  lnn_kernel<<<dim3(B / 2), dim3(256), 0, stream>>>(
      x, mW1, mb1, mW2, mb2, mW3, qW1, qb1, qW2, qb2, qW3, ws4, ws5, ws1, ws6, (float*)d_out);
}